// Round 1
// baseline (372.212 us; speedup 1.0000x reference)
//
#include <hip/hip_runtime.h>
#include <math.h>

// Problem constants (from reference setup_inputs): B=512, C=50000, D=256.
#define D_DIM 256
#define BM 128
#define BN 128
#define BK 16

// ---------------- init: zero accumulators + loaded mask ----------------
__global__ void init_zero(float* ws, int nwords) {
    int i = blockIdx.x * blockDim.x + threadIdx.x;
    if (i < nwords) ws[i] = 0.0f;
}

// ---------------- scatter loaded mask ----------------
__global__ void set_loaded(const int* __restrict__ ids, unsigned char* loaded, int n) {
    int i = blockIdx.x * blockDim.x + threadIdx.x;
    if (i < n) loaded[ids[i]] = 1;
}

// ---------------- row norms: one wave (64 lanes) per row, D=256 = 4 floats/lane --------
__global__ void row_norms(const float* __restrict__ V, const float* __restrict__ T,
                          float* __restrict__ inv_v, float* __restrict__ inv_t,
                          int B, int C) {
    int tid  = threadIdx.x;
    int wave = blockIdx.x * (blockDim.x >> 6) + (tid >> 6);
    int lane = tid & 63;
    if (wave >= B + C) return;  // whole wave uniform
    const float* src = (wave < B) ? (V + (size_t)wave * D_DIM)
                                  : (T + (size_t)(wave - B) * D_DIM);
    float4 x = ((const float4*)src)[lane];
    float ss = x.x * x.x + x.y * x.y + x.z * x.z + x.w * x.w;
    #pragma unroll
    for (int off = 32; off > 0; off >>= 1) ss += __shfl_xor(ss, off);
    if (lane == 0) {
        float nrm = sqrtf(ss);
        if (wave < B) inv_v[wave] = 1.0f / nrm;           // visual: no eps
        else          inv_t[wave - B] = 1.0f / (1e-6f + nrm);  // text: +1e-6 on norm
    }
}

// ---------------- fused GEMM (S = Vn * Tn^T) + masked epilogue reduction ----------------
__global__ __launch_bounds__(256) void gemm_epilogue(
    const float* __restrict__ V, const float* __restrict__ T,
    const int* __restrict__ label, const unsigned char* __restrict__ loaded,
    const float* __restrict__ inv_v, const float* __restrict__ inv_t,
    float* __restrict__ denom, float* __restrict__ pos_sum, float* __restrict__ nposf,
    int C) {
    __shared__ float As[BK][BM];   // A transposed: As[k][m]
    __shared__ float Bs[BK][BN];   // B transposed: Bs[k][n]
    __shared__ float sDen[BM], sPos[BM], sNp[BM];

    int tid = threadIdx.x;
    int m0 = blockIdx.y * BM;
    int n0 = blockIdx.x * BN;
    if (tid < BM) { sDen[tid] = 0.f; sPos[tid] = 0.f; sNp[tid] = 0.f; }

    // staging assignment: 2 threads per tile row, 8 contiguous k-floats each
    int lr = tid >> 1;            // 0..127 tile row
    int lh = (tid & 1) * 8;       // k half: 0 or 8
    int gm = m0 + lr;             // global visual row (always < 512)
    int gc = n0 + lr;             // global text row (may exceed C)
    float a_scale = inv_v[gm];
    float b_scale = (gc < C) ? inv_t[gc] : 0.0f;
    const float* Ap = V + (size_t)gm * D_DIM + lh;
    const float* Bp = T + (size_t)((gc < C) ? gc : 0) * D_DIM + lh;

    // 8x8 micro-tile per thread; 16x16 thread grid
    int tr8 = (tid >> 4) << 3;
    int tc8 = (tid & 15) << 3;

    float acc[8][8];
    #pragma unroll
    for (int i = 0; i < 8; i++)
        #pragma unroll
        for (int j = 0; j < 8; j++) acc[i][j] = 0.f;

    for (int k0 = 0; k0 < D_DIM; k0 += BK) {
        float4 a0 = *(const float4*)(Ap + k0);
        float4 a1 = *(const float4*)(Ap + k0 + 4);
        float4 b0 = *(const float4*)(Bp + k0);
        float4 b1 = *(const float4*)(Bp + k0 + 4);
        __syncthreads();  // previous iter's LDS reads done before overwrite
        As[lh + 0][lr] = a0.x * a_scale; As[lh + 1][lr] = a0.y * a_scale;
        As[lh + 2][lr] = a0.z * a_scale; As[lh + 3][lr] = a0.w * a_scale;
        As[lh + 4][lr] = a1.x * a_scale; As[lh + 5][lr] = a1.y * a_scale;
        As[lh + 6][lr] = a1.z * a_scale; As[lh + 7][lr] = a1.w * a_scale;
        Bs[lh + 0][lr] = b0.x * b_scale; Bs[lh + 1][lr] = b0.y * b_scale;
        Bs[lh + 2][lr] = b0.z * b_scale; Bs[lh + 3][lr] = b0.w * b_scale;
        Bs[lh + 4][lr] = b1.x * b_scale; Bs[lh + 5][lr] = b1.y * b_scale;
        Bs[lh + 6][lr] = b1.z * b_scale; Bs[lh + 7][lr] = b1.w * b_scale;
        __syncthreads();
        #pragma unroll
        for (int k = 0; k < BK; k++) {
            float4 av0 = *(const float4*)&As[k][tr8];
            float4 av1 = *(const float4*)&As[k][tr8 + 4];
            float4 bv0 = *(const float4*)&Bs[k][tc8];
            float4 bv1 = *(const float4*)&Bs[k][tc8 + 4];
            float a[8] = {av0.x, av0.y, av0.z, av0.w, av1.x, av1.y, av1.z, av1.w};
            float b[8] = {bv0.x, bv0.y, bv0.z, bv0.w, bv1.x, bv1.y, bv1.z, bv1.w};
            #pragma unroll
            for (int i = 0; i < 8; i++)
                #pragma unroll
                for (int j = 0; j < 8; j++) acc[i][j] += a[i] * b[j];
        }
    }

    // epilogue: masked per-row partial reduction
    #pragma unroll
    for (int i = 0; i < 8; i++) {
        int r = tr8 + i;
        int gr = m0 + r;
        float den = 0.f, pos = 0.f, np = 0.f;
        #pragma unroll
        for (int j = 0; j < 8; j++) {
            int c = n0 + tc8 + j;
            if (c < C) {
                int lab = label[(size_t)gr * C + c];
                unsigned char ld = loaded[c];
                float s = acc[i][j];
                if (ld) {
                    if (lab) { pos += s; np += 1.0f; }
                    else     { den += __expf(s); }
                }
            }
        }
        if (den != 0.f) atomicAdd(&sDen[r], den);
        if (np  != 0.f) { atomicAdd(&sPos[r], pos); atomicAdd(&sNp[r], np); }
    }
    __syncthreads();
    if (tid < BM) {
        int gr = m0 + tid;
        if (sDen[tid] != 0.f) atomicAdd(&denom[gr], sDen[tid]);
        if (sNp[tid]  != 0.f) { atomicAdd(&pos_sum[gr], sPos[tid]); atomicAdd(&nposf[gr], sNp[tid]); }
    }
}

// ---------------- finalize: per_row = log(denom) - pos_sum/n_pos; mean over B ----------
__global__ void finalize(const float* __restrict__ denom, const float* __restrict__ pos_sum,
                         const float* __restrict__ nposf, float* __restrict__ out, int B) {
    __shared__ float red[512];
    int tid = threadIdx.x;
    float pr = 0.f;
    if (tid < B) pr = logf(denom[tid]) - pos_sum[tid] / nposf[tid];
    red[tid] = pr;
    __syncthreads();
    for (int s = 256; s > 0; s >>= 1) {
        if (tid < s) red[tid] += red[tid + s];
        __syncthreads();
    }
    if (tid == 0) out[0] = red[0] / (float)B;
}

extern "C" void kernel_launch(void* const* d_in, const int* in_sizes, int n_in,
                              void* d_out, int out_size, void* d_ws, size_t ws_size,
                              hipStream_t stream) {
    const float* V     = (const float*)d_in[0];
    const float* T     = (const float*)d_in[1];
    const int*   label = (const int*)d_in[2];
    const int*   ids   = (const int*)d_in[3];
    int B = in_sizes[0] / D_DIM;   // 512
    int C = in_sizes[1] / D_DIM;   // 50000
    int n_loaded = in_sizes[3];    // 40000

    // ws layout (bytes):
    //   0      : denom   [512 f]
    //   2048   : pos_sum [512 f]
    //   4096   : nposf   [512 f]
    //   6144   : loaded mask [C bytes, padded to 50176]
    //   56320  : inv_v [512 f]
    //   58368  : inv_t [C f]  (ends at 258368)
    char* ws = (char*)d_ws;
    float* denom   = (float*)(ws + 0);
    float* pos_sum = (float*)(ws + 2048);
    float* nposf   = (float*)(ws + 4096);
    unsigned char* loaded = (unsigned char*)(ws + 6144);
    float* inv_v   = (float*)(ws + 56320);
    float* inv_t   = (float*)(ws + 58368);

    int zero_words = (6144 + 50176) / 4;  // accumulators + mask
    init_zero<<<(zero_words + 255) / 256, 256, 0, stream>>>((float*)ws, zero_words);
    set_loaded<<<(n_loaded + 255) / 256, 256, 0, stream>>>(ids, loaded, n_loaded);

    int waves = B + C;
    row_norms<<<(waves + 3) / 4, 256, 0, stream>>>(V, T, inv_v, inv_t, B, C);

    dim3 grid((C + BN - 1) / BN, B / BM);
    gemm_epilogue<<<grid, 256, 0, stream>>>(V, T, label, loaded, inv_v, inv_t,
                                            denom, pos_sum, nposf, C);

    finalize<<<1, 512, 0, stream>>>(denom, pos_sum, nposf, (float*)d_out, B);
}

// Round 2
// 334.706 us; speedup vs baseline: 1.1121x; 1.1121x over previous
//
#include <hip/hip_runtime.h>
#include <math.h>

// Problem constants: B=512, C=50000, D=256.
#define D_DIM 256
#define TM 128
#define TN 128
#define LSTR 40   // LDS row stride in bf16 elems (80 B = multiple of 16 B, breaks bank pattern)

typedef __attribute__((ext_vector_type(8))) short short8;
typedef __attribute__((ext_vector_type(4))) float floatx4;

__device__ __forceinline__ unsigned short f2bf(float f) {
    unsigned int u = __float_as_uint(f);
    u += 0x7FFFu + ((u >> 16) & 1u);   // round-to-nearest-even
    return (unsigned short)(u >> 16);
}

__device__ __forceinline__ short8 pack8(float4 x, float4 y, float s) {
    short8 r;
    r[0] = (short)f2bf(x.x * s); r[1] = (short)f2bf(x.y * s);
    r[2] = (short)f2bf(x.z * s); r[3] = (short)f2bf(x.w * s);
    r[4] = (short)f2bf(y.x * s); r[5] = (short)f2bf(y.y * s);
    r[6] = (short)f2bf(y.z * s); r[7] = (short)f2bf(y.w * s);
    return r;
}

// ---------------- init: zero accumulators + loaded mask ----------------
__global__ void init_zero(float* ws, int nwords) {
    int i = blockIdx.x * blockDim.x + threadIdx.x;
    if (i < nwords) ws[i] = 0.0f;
}

// ---------------- row norms (one wave per row) + scatter loaded mask ----------------
__global__ void norms_scatter(const float* __restrict__ V, const float* __restrict__ T,
                              const int* __restrict__ ids, unsigned char* loaded,
                              float* __restrict__ inv_v, float* __restrict__ inv_t,
                              int B, int C, int n_loaded) {
    int gtid = blockIdx.x * blockDim.x + threadIdx.x;
    if (gtid < n_loaded) loaded[ids[gtid]] = 1;

    int wave = gtid >> 6;
    int lane = threadIdx.x & 63;
    if (wave >= B + C) return;  // whole wave uniform
    const float* src = (wave < B) ? (V + (size_t)wave * D_DIM)
                                  : (T + (size_t)(wave - B) * D_DIM);
    float4 x = ((const float4*)src)[lane];
    float ss = x.x * x.x + x.y * x.y + x.z * x.z + x.w * x.w;
    #pragma unroll
    for (int off = 32; off > 0; off >>= 1) ss += __shfl_xor(ss, off);
    if (lane == 0) {
        float nrm = sqrtf(ss);
        if (wave < B) inv_v[wave] = 1.0f / nrm;                 // visual: no eps
        else          inv_t[wave - B] = 1.0f / (1e-6f + nrm);   // text: +1e-6 on norm
    }
}

// ---------------- bf16 MFMA GEMM (S = Vn * Tn^T) + fused masked epilogue ----------------
__global__ __launch_bounds__(256) void gemm_mfma(
    const float* __restrict__ V, const float* __restrict__ T,
    const int* __restrict__ label, const unsigned char* __restrict__ loaded,
    const float* __restrict__ inv_v, const float* __restrict__ inv_t,
    float* __restrict__ denom, float* __restrict__ pos_sum, float* __restrict__ nposf,
    int C) {
    __shared__ unsigned short As[TM * LSTR];   // [row][k] bf16, stride 40
    __shared__ unsigned short Bs[TN * LSTR];
    __shared__ float sDen[TM], sPos[TM], sNp[TM];
    __shared__ unsigned char sLoaded[TN];

    const int tid  = threadIdx.x;
    const int lane = tid & 63;
    const int w    = tid >> 6;
    const int m0 = blockIdx.y * TM;
    const int n0 = blockIdx.x * TN;

    if (tid < TM) { sDen[tid] = 0.f; sPos[tid] = 0.f; sNp[tid] = 0.f; }
    if (tid < TN) { int c = n0 + tid; sLoaded[tid] = (c < C) ? loaded[c] : (unsigned char)0; }

    // ---- staging: wave w stages tile rows [w*32, w*32+32) of A and B (2 issues of 16 rows)
    const int sr = lane >> 2;          // 0..15 row within issue
    const int kq = lane & 3;           // k-chunk 0..3 (8 floats each)
    const int kb = kq * 8;
    const int ra0 = w * 32 + sr;       // issue-0 tile row; issue-1 = +16
    const int gm0 = m0 + ra0, gm1 = gm0 + 16;
    const float sa0 = inv_v[gm0], sa1 = inv_v[gm1];
    int gc0 = n0 + ra0, gc1 = gc0 + 16;
    const float sb0 = (gc0 < C) ? inv_t[gc0] : 0.f;
    const float sb1 = (gc1 < C) ? inv_t[gc1] : 0.f;
    if (gc0 >= C) gc0 = 0;
    if (gc1 >= C) gc1 = 0;
    const float* pa0 = V + (size_t)gm0 * D_DIM + kb;
    const float* pa1 = V + (size_t)gm1 * D_DIM + kb;
    const float* pb0 = T + (size_t)gc0 * D_DIM + kb;
    const float* pb1 = T + (size_t)gc1 * D_DIM + kb;
    unsigned short* wa0 = &As[ra0 * LSTR + kb];
    unsigned short* wa1 = &As[(ra0 + 16) * LSTR + kb];
    unsigned short* wb0 = &Bs[ra0 * LSTR + kb];
    unsigned short* wb1 = &Bs[(ra0 + 16) * LSTR + kb];

    // ---- compute-side: 2x2 waves, each 64x64 via 4x4 fragments of 16x16x32
    const int wm = (w >> 1) * 64;
    const int wn = (w & 1) * 64;
    const int fr = lane & 15;
    const int quad = lane >> 4;

    floatx4 acc[4][4];
    #pragma unroll
    for (int mi = 0; mi < 4; mi++)
        #pragma unroll
        for (int ni = 0; ni < 4; ni++) acc[mi][ni] = (floatx4)0.f;

    float4 a00 = *(const float4*)(pa0 + 0), a01 = *(const float4*)(pa0 + 4);
    float4 a10 = *(const float4*)(pa1 + 0), a11 = *(const float4*)(pa1 + 4);
    float4 b00 = *(const float4*)(pb0 + 0), b01 = *(const float4*)(pb0 + 4);
    float4 b10 = *(const float4*)(pb1 + 0), b11 = *(const float4*)(pb1 + 4);

    #pragma unroll
    for (int kt = 0; kt < D_DIM / 32; ++kt) {
        if (kt) __syncthreads();  // protect previous iter's frag reads
        *(short8*)wa0 = pack8(a00, a01, sa0);
        *(short8*)wa1 = pack8(a10, a11, sa1);
        *(short8*)wb0 = pack8(b00, b01, sb0);
        *(short8*)wb1 = pack8(b10, b11, sb1);
        if (kt + 1 < D_DIM / 32) {
            int ko = (kt + 1) * 32;
            a00 = *(const float4*)(pa0 + ko); a01 = *(const float4*)(pa0 + ko + 4);
            a10 = *(const float4*)(pa1 + ko); a11 = *(const float4*)(pa1 + ko + 4);
            b00 = *(const float4*)(pb0 + ko); b01 = *(const float4*)(pb0 + ko + 4);
            b10 = *(const float4*)(pb1 + ko); b11 = *(const float4*)(pb1 + ko + 4);
        }
        __syncthreads();
        short8 af[4], bf[4];
        #pragma unroll
        for (int mi = 0; mi < 4; mi++)
            af[mi] = *(const short8*)&As[(wm + mi * 16 + fr) * LSTR + quad * 8];
        #pragma unroll
        for (int ni = 0; ni < 4; ni++)
            bf[ni] = *(const short8*)&Bs[(wn + ni * 16 + fr) * LSTR + quad * 8];
        #pragma unroll
        for (int mi = 0; mi < 4; mi++)
            #pragma unroll
            for (int ni = 0; ni < 4; ni++)
                acc[mi][ni] = __builtin_amdgcn_mfma_f32_16x16x32_bf16(
                    af[mi], bf[ni], acc[mi][ni], 0, 0, 0);
    }

    // ---- epilogue: masked per-row reduction.
    // D layout: row = quad*4 + reg, col = lane&15 (within each 16x16 fragment).
    #pragma unroll
    for (int mi = 0; mi < 4; mi++) {
        #pragma unroll
        for (int i = 0; i < 4; i++) {
            const int mloc = wm + mi * 16 + quad * 4 + i;
            const int gr = m0 + mloc;
            float den = 0.f, pos = 0.f, np = 0.f;
            #pragma unroll
            for (int ni = 0; ni < 4; ni++) {
                const int nloc = wn + ni * 16 + fr;
                const int gc = n0 + nloc;
                if (sLoaded[nloc]) {   // OOB cols have sLoaded=0
                    float s = acc[mi][ni][i];
                    int lab = label[(size_t)gr * C + gc];
                    if (lab) { pos += s; np += 1.f; }
                    else     { den += __expf(s); }
                }
            }
            // reduce across the 16 lanes of this quad (same output row)
            #pragma unroll
            for (int off = 8; off >= 1; off >>= 1) {
                den += __shfl_xor(den, off);
                pos += __shfl_xor(pos, off);
                np  += __shfl_xor(np, off);
            }
            if (fr == 0) {
                if (den != 0.f) atomicAdd(&sDen[mloc], den);
                if (np  != 0.f) { atomicAdd(&sPos[mloc], pos); atomicAdd(&sNp[mloc], np); }
            }
        }
    }
    __syncthreads();
    if (tid < TM) {
        int gr = m0 + tid;
        if (sDen[tid] != 0.f) atomicAdd(&denom[gr], sDen[tid]);
        if (sNp[tid]  != 0.f) { atomicAdd(&pos_sum[gr], sPos[tid]); atomicAdd(&nposf[gr], sNp[tid]); }
    }
}

// ---------------- finalize ----------------
__global__ void finalize(const float* __restrict__ denom, const float* __restrict__ pos_sum,
                         const float* __restrict__ nposf, float* __restrict__ out, int B) {
    __shared__ float red[512];
    int tid = threadIdx.x;
    float pr = 0.f;
    if (tid < B) pr = logf(denom[tid]) - pos_sum[tid] / nposf[tid];
    red[tid] = pr;
    __syncthreads();
    for (int s = 256; s > 0; s >>= 1) {
        if (tid < s) red[tid] += red[tid + s];
        __syncthreads();
    }
    if (tid == 0) out[0] = red[0] / (float)B;
}

extern "C" void kernel_launch(void* const* d_in, const int* in_sizes, int n_in,
                              void* d_out, int out_size, void* d_ws, size_t ws_size,
                              hipStream_t stream) {
    const float* V     = (const float*)d_in[0];
    const float* T     = (const float*)d_in[1];
    const int*   label = (const int*)d_in[2];
    const int*   ids   = (const int*)d_in[3];
    int B = in_sizes[0] / D_DIM;   // 512
    int C = in_sizes[1] / D_DIM;   // 50000
    int n_loaded = in_sizes[3];    // 40000

    // ws layout (bytes):
    //   0      : denom   [512 f]
    //   2048   : pos_sum [512 f]
    //   4096   : nposf   [512 f]
    //   6144   : loaded mask [C bytes, padded to 50176]
    //   56320  : inv_v [512 f]
    //   58368  : inv_t [C f]
    char* ws = (char*)d_ws;
    float* denom   = (float*)(ws + 0);
    float* pos_sum = (float*)(ws + 2048);
    float* nposf   = (float*)(ws + 4096);
    unsigned char* loaded = (unsigned char*)(ws + 6144);
    float* inv_v   = (float*)(ws + 56320);
    float* inv_t   = (float*)(ws + 58368);

    int zero_words = (6144 + 50176) / 4;  // accumulators + mask
    init_zero<<<(zero_words + 255) / 256, 256, 0, stream>>>((float*)ws, zero_words);

    int waves = B + C;
    int threads_needed = waves * 64;
    norms_scatter<<<(threads_needed + 255) / 256, 256, 0, stream>>>(
        V, T, ids, loaded, inv_v, inv_t, B, C, n_loaded);

    dim3 grid((C + TN - 1) / TN, B / TM);
    gemm_mfma<<<grid, 256, 0, stream>>>(V, T, label, loaded, inv_v, inv_t,
                                        denom, pos_sum, nposf, C);

    finalize<<<1, 512, 0, stream>>>(denom, pos_sum, nposf, (float*)d_out, B);
}